// Round 1
// baseline (125.573 us; speedup 1.0000x reference)
//
#include <hip/hip_runtime.h>
#include <math.h>

// Problem constants (fixed by setup_inputs): B=8, M=256, D=768, K=100
#define NROWS 2048
#define DDIM  768
#define KNEG  100
#define NLOGITS (KNEG + 1)

static constexpr float TEMP_INV = 10.0f;   // 1 / 0.1
static constexpr float EPS_NORM = 1e-8f;

// Kernel 1: per-row inverse L2 norms for preds and targets.
// One block per row, 256 threads.
__global__ void cl_norms_kernel(const float* __restrict__ preds,
                                const float* __restrict__ targets,
                                float* __restrict__ pinv,
                                float* __restrict__ tinv) {
    const int row = blockIdx.x;
    const int tid = threadIdx.x;
    const float* p = preds   + (size_t)row * DDIM;
    const float* t = targets + (size_t)row * DDIM;
    float sp = 0.f, st = 0.f;
    for (int d = tid; d < DDIM; d += 256) {
        float a = p[d]; sp = fmaf(a, a, sp);
        float b = t[d]; st = fmaf(b, b, st);
    }
    // 64-lane wave reduce
    #pragma unroll
    for (int off = 32; off > 0; off >>= 1) {
        sp += __shfl_down(sp, off);
        st += __shfl_down(st, off);
    }
    __shared__ float sP[4], sT[4];
    const int wave = tid >> 6, lane = tid & 63;
    if (lane == 0) { sP[wave] = sp; sT[wave] = st; }
    __syncthreads();
    if (tid == 0) {
        float tp = sP[0] + sP[1] + sP[2] + sP[3];
        float tt = sT[0] + sT[1] + sT[2] + sT[3];
        pinv[row] = 1.0f / fmaxf(sqrtf(tp), EPS_NORM);
        tinv[row] = 1.0f / fmaxf(sqrtf(tt), EPS_NORM);
    }
}

// Kernel 2: one block per row. Stage normalized pred row in LDS, compute
// 101 dot products (pos + 100 gathered negatives), then logsumexp.
__global__ void cl_rowloss_kernel(const float* __restrict__ preds,
                                  const float* __restrict__ targets,
                                  const int* __restrict__ neg_idx,
                                  const float* __restrict__ pinv,
                                  const float* __restrict__ tinv,
                                  float* __restrict__ row_loss) {
    const int i = blockIdx.x;
    const int tid = threadIdx.x;
    const int wave = tid >> 6, lane = tid & 63;

    __shared__ float pn[DDIM];          // normalized pred row (3 KB)
    __shared__ float logits[NLOGITS];   // 101 scaled similarities

    const float pscale = pinv[i];
    const float* p = preds + (size_t)i * DDIM;
    for (int d = tid; d < DDIM; d += 256) pn[d] = p[d] * pscale;
    __syncthreads();

    // 4 waves stride over the 101 dots
    for (int j = wave; j < NLOGITS; j += 4) {
        const int row = (j == 0) ? i : neg_idx[(size_t)i * KNEG + (j - 1)];
        const float* t = targets + (size_t)row * DDIM;
        float acc = 0.f;
        #pragma unroll
        for (int d = lane; d < DDIM; d += 64) acc = fmaf(pn[d], t[d], acc);
        #pragma unroll
        for (int off = 32; off > 0; off >>= 1) acc += __shfl_down(acc, off);
        if (lane == 0) logits[j] = acc * tinv[row] * TEMP_INV;
    }
    __syncthreads();

    // wave 0: logsumexp over 101 logits; loss_i = lse - logits[0]
    if (wave == 0) {
        float v0 = (lane < NLOGITS)      ? logits[lane]      : -INFINITY;
        float v1 = (lane + 64 < NLOGITS) ? logits[lane + 64] : -INFINITY;
        float m = fmaxf(v0, v1);
        #pragma unroll
        for (int off = 32; off > 0; off >>= 1) m = fmaxf(m, __shfl_down(m, off));
        m = __shfl(m, 0);
        float e = 0.f;
        if (lane < NLOGITS)      e += expf(v0 - m);
        if (lane + 64 < NLOGITS) e += expf(v1 - m);
        #pragma unroll
        for (int off = 32; off > 0; off >>= 1) e += __shfl_down(e, off);
        if (lane == 0) row_loss[i] = (m + logf(e)) - logits[0];
    }
}

// Kernel 3: deterministic final mean over the 2048 row losses.
__global__ void cl_reduce_kernel(const float* __restrict__ row_loss,
                                 float* __restrict__ out) {
    const int tid = threadIdx.x; // 256
    float s = 0.f;
    for (int i = tid; i < NROWS; i += 256) s += row_loss[i];
    #pragma unroll
    for (int off = 32; off > 0; off >>= 1) s += __shfl_down(s, off);
    __shared__ float sw[4];
    const int wave = tid >> 6, lane = tid & 63;
    if (lane == 0) sw[wave] = s;
    __syncthreads();
    if (tid == 0) out[0] = (sw[0] + sw[1] + sw[2] + sw[3]) / (float)NROWS;
}

extern "C" void kernel_launch(void* const* d_in, const int* in_sizes, int n_in,
                              void* d_out, int out_size, void* d_ws, size_t ws_size,
                              hipStream_t stream) {
    const float* preds   = (const float*)d_in[0];
    const float* targets = (const float*)d_in[1];
    const int*   neg_idx = (const int*)d_in[2];
    float* out = (float*)d_out;

    // workspace layout: pinv[N] | tinv[N] | row_loss[N]  (24 KB total)
    float* pinv     = (float*)d_ws;
    float* tinv     = pinv + NROWS;
    float* row_loss = tinv + NROWS;

    cl_norms_kernel<<<NROWS, 256, 0, stream>>>(preds, targets, pinv, tinv);
    cl_rowloss_kernel<<<NROWS, 256, 0, stream>>>(preds, targets, neg_idx,
                                                 pinv, tinv, row_loss);
    cl_reduce_kernel<<<1, 256, 0, stream>>>(row_loss, out);
}

// Round 2
// 42.508 us; speedup vs baseline: 2.9541x; 2.9541x over previous
//
#include <hip/hip_runtime.h>
#include <hip/hip_bf16.h>
#include <math.h>

// Problem constants (fixed by setup_inputs): B=8, M=256, D=768, K=100
#define NROWS 2048
#define DDIM  768
#define KNEG  100
#define NLOGITS (KNEG + 1)

static constexpr float TEMP_INV = 10.0f;   // 1 / 0.1
static constexpr float EPS_NORM = 1e-8f;

__device__ __forceinline__ float bf_lo(unsigned u) { return __uint_as_float(u << 16); }
__device__ __forceinline__ float bf_hi(unsigned u) { return __uint_as_float(u & 0xffff0000u); }

// Kernel 1: per-row pred inverse-norm + normalized targets in bf16.
// tn_bf16 is 2048x768x2B = 3 MB -> fits each XCD's 4 MiB L2 for the gather.
__global__ void cl_prep_kernel(const float* __restrict__ preds,
                               const float* __restrict__ targets,
                               float* __restrict__ pinv,
                               __hip_bfloat16* __restrict__ tn) {
    const int row = blockIdx.x;
    const int tid = threadIdx.x;   // 256
    const float* p = preds   + (size_t)row * DDIM;
    const float* t = targets + (size_t)row * DDIM;
    float tv[3];
    float sp = 0.f, st = 0.f;
    #pragma unroll
    for (int c = 0; c < 3; ++c) {
        float a = p[tid + 256 * c]; sp = fmaf(a, a, sp);
        float b = t[tid + 256 * c]; tv[c] = b; st = fmaf(b, b, st);
    }
    #pragma unroll
    for (int off = 32; off > 0; off >>= 1) {
        sp += __shfl_down(sp, off);
        st += __shfl_down(st, off);
    }
    __shared__ float sP[4], sT[4];
    const int wave = tid >> 6, lane = tid & 63;
    if (lane == 0) { sP[wave] = sp; sT[wave] = st; }
    __syncthreads();
    const float tp = sP[0] + sP[1] + sP[2] + sP[3];
    const float tt = sT[0] + sT[1] + sT[2] + sT[3];
    if (tid == 0) pinv[row] = 1.0f / fmaxf(sqrtf(tp), EPS_NORM);
    const float it = 1.0f / fmaxf(sqrtf(tt), EPS_NORM);
    __hip_bfloat16* trow = tn + (size_t)row * DDIM;
    #pragma unroll
    for (int c = 0; c < 3; ++c)
        trow[tid + 256 * c] = __float2bfloat16(tv[c] * it);
}

// Kernel 2: one block per pred row. Pred row normalized into REGISTERS
// (12 floats/lane); 4 waves split the 101 logits; 4 dots in flight per wave
// with vectorized bf16 gather loads; shuffle-reduce; then logsumexp.
__global__ __launch_bounds__(256) void cl_rowloss_kernel(
        const float* __restrict__ preds,
        const __hip_bfloat16* __restrict__ tn,
        const int* __restrict__ neg_idx,
        const float* __restrict__ pinv,
        float* __restrict__ row_loss) {
    const int i = blockIdx.x;
    const int tid = threadIdx.x;
    const int wave = tid >> 6, lane = tid & 63;

    __shared__ float logits[NLOGITS];

    // Pred fragment: lane holds d = 256*c + 4*lane + k  (c<3, k<4)
    const float ps = pinv[i];
    const float4* pv = (const float4*)(preds + (size_t)i * DDIM);
    float pf[3][4];
    #pragma unroll
    for (int c = 0; c < 3; ++c) {
        float4 v = pv[lane + 64 * c];
        pf[c][0] = v.x * ps; pf[c][1] = v.y * ps;
        pf[c][2] = v.z * ps; pf[c][3] = v.w * ps;
    }

    // Contiguous j-ranges per wave: 26,25,25,25
    const int jbeg = wave * 25 + (wave ? 1 : 0);
    const int jend = jbeg + (wave ? 25 : 26);

    for (int j0 = jbeg; j0 < jend; j0 += 4) {
        int rows[4];
        #pragma unroll
        for (int s = 0; s < 4; ++s) {
            const int j = j0 + s;
            rows[s] = (j < jend) ? ((j == 0) ? i : neg_idx[(size_t)i * KNEG + (j - 1)])
                                 : i;  // safe dummy for tail
        }
        // Issue all 12 gather loads (uint2 = 4 bf16) before any FMA.
        uint2 u[4][3];
        #pragma unroll
        for (int s = 0; s < 4; ++s) {
            const uint2* tp2 = (const uint2*)(tn + (size_t)rows[s] * DDIM) + lane;
            u[s][0] = tp2[0]; u[s][1] = tp2[64]; u[s][2] = tp2[128];
        }
        float acc[4] = {0.f, 0.f, 0.f, 0.f};
        #pragma unroll
        for (int s = 0; s < 4; ++s)
            #pragma unroll
            for (int c = 0; c < 3; ++c) {
                acc[s] = fmaf(pf[c][0], bf_lo(u[s][c].x), acc[s]);
                acc[s] = fmaf(pf[c][1], bf_hi(u[s][c].x), acc[s]);
                acc[s] = fmaf(pf[c][2], bf_lo(u[s][c].y), acc[s]);
                acc[s] = fmaf(pf[c][3], bf_hi(u[s][c].y), acc[s]);
            }
        // 4 independent shuffle reductions (interleaved by the scheduler)
        #pragma unroll
        for (int s = 0; s < 4; ++s) {
            float a = acc[s];
            #pragma unroll
            for (int off = 32; off > 0; off >>= 1) a += __shfl_down(a, off);
            if (lane == 0 && (j0 + s) < jend) logits[j0 + s] = a * TEMP_INV;
        }
    }
    __syncthreads();

    // wave 0: logsumexp over 101 logits; loss_i = lse - logits[0]
    if (wave == 0) {
        float v0 = (lane < NLOGITS)      ? logits[lane]      : -INFINITY;
        float v1 = (lane + 64 < NLOGITS) ? logits[lane + 64] : -INFINITY;
        float m = fmaxf(v0, v1);
        #pragma unroll
        for (int off = 32; off > 0; off >>= 1) m = fmaxf(m, __shfl_down(m, off));
        m = __shfl(m, 0);
        float e = 0.f;
        if (lane < NLOGITS)      e += expf(v0 - m);
        if (lane + 64 < NLOGITS) e += expf(v1 - m);
        #pragma unroll
        for (int off = 32; off > 0; off >>= 1) e += __shfl_down(e, off);
        if (lane == 0) row_loss[i] = (m + logf(e)) - logits[0];
    }
}

// Kernel 3: deterministic final mean over the 2048 row losses.
__global__ void cl_reduce_kernel(const float* __restrict__ row_loss,
                                 float* __restrict__ out) {
    const int tid = threadIdx.x; // 256
    float s = 0.f;
    for (int i = tid; i < NROWS; i += 256) s += row_loss[i];
    #pragma unroll
    for (int off = 32; off > 0; off >>= 1) s += __shfl_down(s, off);
    __shared__ float sw[4];
    const int wave = tid >> 6, lane = tid & 63;
    if (lane == 0) sw[wave] = s;
    __syncthreads();
    if (tid == 0) out[0] = (sw[0] + sw[1] + sw[2] + sw[3]) / (float)NROWS;
}

extern "C" void kernel_launch(void* const* d_in, const int* in_sizes, int n_in,
                              void* d_out, int out_size, void* d_ws, size_t ws_size,
                              hipStream_t stream) {
    const float* preds   = (const float*)d_in[0];
    const float* targets = (const float*)d_in[1];
    const int*   neg_idx = (const int*)d_in[2];
    float* out = (float*)d_out;

    // workspace: tn_bf16 (3 MB, 8B-aligned at base) | pinv[N] | row_loss[N]
    __hip_bfloat16* tn = (__hip_bfloat16*)d_ws;
    float* pinv     = (float*)((char*)d_ws + (size_t)NROWS * DDIM * sizeof(__hip_bfloat16));
    float* row_loss = pinv + NROWS;

    cl_prep_kernel<<<NROWS, 256, 0, stream>>>(preds, targets, pinv, tn);
    cl_rowloss_kernel<<<NROWS, 256, 0, stream>>>(preds, tn, neg_idx, pinv, row_loss);
    cl_reduce_kernel<<<1, 256, 0, stream>>>(row_loss, out);
}

// Round 3
// 39.098 us; speedup vs baseline: 3.2117x; 1.0872x over previous
//
#include <hip/hip_runtime.h>
#include <hip/hip_bf16.h>
#include <math.h>

// Problem constants (fixed by setup_inputs): B=8, M=256, D=768, K=100
#define NROWS 2048
#define DDIM  768
#define KNEG  100
#define NLOGITS (KNEG + 1)

static constexpr float TEMP_INV = 10.0f;   // 1 / 0.1
static constexpr float EPS_NORM = 1e-8f;

__device__ __forceinline__ float bf_lo(unsigned u) { return __uint_as_float(u << 16); }
__device__ __forceinline__ float bf_hi(unsigned u) { return __uint_as_float(u & 0xffff0000u); }
__device__ __forceinline__ unsigned pack_bf2(float a, float b) {
    __hip_bfloat16 ha = __float2bfloat16(a), hb = __float2bfloat16(b);
    unsigned short sa, sb;
    __builtin_memcpy(&sa, &ha, 2);
    __builtin_memcpy(&sb, &hb, 2);
    return (unsigned)sa | ((unsigned)sb << 16);
}

// Shared register layout for a 768-dim row, one wave (64 lanes), 12 elems/lane:
//   chunk A: dims 8*lane+k   (k<8)  -> float4 pair / one uint4 (8 bf16)
//   chunk B: dims 512+4*lane+k (k<4) -> one float4 / one uint2 (4 bf16)

// Kernel 1: normalize target rows -> bf16 (3 MB total; L2-resident for gather).
// One wave per row, 4 rows per block.
__global__ __launch_bounds__(256) void cl_prep_kernel(
        const float* __restrict__ targets,
        __hip_bfloat16* __restrict__ tn) {
    const int wave = threadIdx.x >> 6, lane = threadIdx.x & 63;
    const int row = blockIdx.x * 4 + wave;
    const float4* tv = (const float4*)(targets + (size_t)row * DDIM);
    const float4 a0 = tv[2 * lane], a1 = tv[2 * lane + 1], b0 = tv[128 + lane];

    float ss = 0.f;
    ss = fmaf(a0.x, a0.x, ss); ss = fmaf(a0.y, a0.y, ss);
    ss = fmaf(a0.z, a0.z, ss); ss = fmaf(a0.w, a0.w, ss);
    ss = fmaf(a1.x, a1.x, ss); ss = fmaf(a1.y, a1.y, ss);
    ss = fmaf(a1.z, a1.z, ss); ss = fmaf(a1.w, a1.w, ss);
    ss = fmaf(b0.x, b0.x, ss); ss = fmaf(b0.y, b0.y, ss);
    ss = fmaf(b0.z, b0.z, ss); ss = fmaf(b0.w, b0.w, ss);
    #pragma unroll
    for (int off = 32; off > 0; off >>= 1) ss += __shfl_xor(ss, off);
    const float it = 1.0f / fmaxf(sqrtf(ss), EPS_NORM);

    uint4 ua;
    ua.x = pack_bf2(a0.x * it, a0.y * it);
    ua.y = pack_bf2(a0.z * it, a0.w * it);
    ua.z = pack_bf2(a1.x * it, a1.y * it);
    ua.w = pack_bf2(a1.z * it, a1.w * it);
    uint2 ub;
    ub.x = pack_bf2(b0.x * it, b0.y * it);
    ub.y = pack_bf2(b0.z * it, b0.w * it);

    __hip_bfloat16* trow = tn + (size_t)row * DDIM;
    ((uint4*)trow)[lane] = ua;
    ((uint2*)(trow + 512))[lane] = ub;
}

// Kernel 2: one block per pred row; 4 waves split the 101 logits.
// Pred row + its norm computed in-registers; indices preloaded lane-parallel;
// gather double-buffered 4 logits deep; shuffle-reduce; wave0 logsumexp.
__global__ __launch_bounds__(256) void cl_rowloss_kernel(
        const float* __restrict__ preds,
        const __hip_bfloat16* __restrict__ tn,
        const int* __restrict__ neg_idx,
        float* __restrict__ row_loss) {
    const int i = blockIdx.x;
    const int wave = threadIdx.x >> 6, lane = threadIdx.x & 63;

    __shared__ float logits[NLOGITS];

    // Pred fragment (raw, unnormalized) + in-wave norm
    const float4* pv = (const float4*)(preds + (size_t)i * DDIM);
    const float4 pa0 = pv[2 * lane], pa1 = pv[2 * lane + 1], pb0 = pv[128 + lane];
    float pf[12] = {pa0.x, pa0.y, pa0.z, pa0.w,
                    pa1.x, pa1.y, pa1.z, pa1.w,
                    pb0.x, pb0.y, pb0.z, pb0.w};
    float ss = 0.f;
    #pragma unroll
    for (int k = 0; k < 12; ++k) ss = fmaf(pf[k], pf[k], ss);
    #pragma unroll
    for (int off = 32; off > 0; off >>= 1) ss += __shfl_xor(ss, off);
    const float psT = TEMP_INV / fmaxf(sqrtf(ss), EPS_NORM);

    // Contiguous logit ranges per wave: 26,25,25,25
    const int jbeg = wave * 25 + (wave ? 1 : 0);
    const int cnt  = wave ? 25 : 26;

    // Preload this wave's gather rows, one per lane
    int rowreg = i;
    if (lane < cnt) {
        const int j = jbeg + lane;
        if (j != 0) rowreg = neg_idx[(size_t)i * KNEG + j - 1];
    }

    const int nb = (cnt + 3) >> 2;   // 7 batches of up to 4 logits
    uint4 A[2][4];
    uint2 B[2][4];

    auto prefetch = [&](int b, int buf) {
        #pragma unroll
        for (int s = 0; s < 4; ++s) {
            int t = b * 4 + s;
            if (t > cnt - 1) t = cnt - 1;          // tail: duplicate last row
            const int r = __shfl(rowreg, t);
            const __hip_bfloat16* trow = tn + (size_t)r * DDIM;
            A[buf][s] = ((const uint4*)trow)[lane];
            B[buf][s] = ((const uint2*)(trow + 512))[lane];
        }
    };

    auto compute = [&](int b, int buf) {
        float acc[4];
        #pragma unroll
        for (int s = 0; s < 4; ++s) {
            const uint4 a = A[buf][s];
            const uint2 bb = B[buf][s];
            float v = 0.f;
            v = fmaf(pf[0],  bf_lo(a.x),  v); v = fmaf(pf[1],  bf_hi(a.x),  v);
            v = fmaf(pf[2],  bf_lo(a.y),  v); v = fmaf(pf[3],  bf_hi(a.y),  v);
            v = fmaf(pf[4],  bf_lo(a.z),  v); v = fmaf(pf[5],  bf_hi(a.z),  v);
            v = fmaf(pf[6],  bf_lo(a.w),  v); v = fmaf(pf[7],  bf_hi(a.w),  v);
            v = fmaf(pf[8],  bf_lo(bb.x), v); v = fmaf(pf[9],  bf_hi(bb.x), v);
            v = fmaf(pf[10], bf_lo(bb.y), v); v = fmaf(pf[11], bf_hi(bb.y), v);
            acc[s] = v;
        }
        #pragma unroll
        for (int s = 0; s < 4; ++s) {
            float a = acc[s];
            #pragma unroll
            for (int off = 32; off > 0; off >>= 1) a += __shfl_down(a, off);
            const int t = b * 4 + s;
            if (lane == 0 && t < cnt) logits[jbeg + t] = a * psT;
        }
    };

    prefetch(0, 0);
    for (int b = 0; b < nb; ++b) {
        if (b + 1 < nb) prefetch(b + 1, (b + 1) & 1);
        compute(b, b & 1);
    }
    __syncthreads();

    // wave 0: logsumexp over 101 logits; loss_i = lse - logits[0]
    if (wave == 0) {
        const float v0 = (lane < NLOGITS)      ? logits[lane]      : -INFINITY;
        const float v1 = (lane + 64 < NLOGITS) ? logits[lane + 64] : -INFINITY;
        float m = fmaxf(v0, v1);
        #pragma unroll
        for (int off = 32; off > 0; off >>= 1) m = fmaxf(m, __shfl_down(m, off));
        m = __shfl(m, 0);
        float e = 0.f;
        if (lane < NLOGITS)      e += expf(v0 - m);
        if (lane + 64 < NLOGITS) e += expf(v1 - m);
        #pragma unroll
        for (int off = 32; off > 0; off >>= 1) e += __shfl_down(e, off);
        if (lane == 0) row_loss[i] = (m + logf(e)) - logits[0];
    }
}

// Kernel 3: deterministic final mean over the 2048 row losses.
__global__ void cl_reduce_kernel(const float* __restrict__ row_loss,
                                 float* __restrict__ out) {
    const int tid = threadIdx.x; // 256
    float s = 0.f;
    for (int i = tid; i < NROWS; i += 256) s += row_loss[i];
    #pragma unroll
    for (int off = 32; off > 0; off >>= 1) s += __shfl_down(s, off);
    __shared__ float sw[4];
    const int wave = tid >> 6, lane = tid & 63;
    if (lane == 0) sw[wave] = s;
    __syncthreads();
    if (tid == 0) out[0] = (sw[0] + sw[1] + sw[2] + sw[3]) / (float)NROWS;
}

extern "C" void kernel_launch(void* const* d_in, const int* in_sizes, int n_in,
                              void* d_out, int out_size, void* d_ws, size_t ws_size,
                              hipStream_t stream) {
    const float* preds   = (const float*)d_in[0];
    const float* targets = (const float*)d_in[1];
    const int*   neg_idx = (const int*)d_in[2];
    float* out = (float*)d_out;

    // workspace: tn_bf16 (3 MB, 16B-aligned at base) | row_loss[N]
    __hip_bfloat16* tn = (__hip_bfloat16*)d_ws;
    float* row_loss = (float*)((char*)d_ws + (size_t)NROWS * DDIM * sizeof(__hip_bfloat16));

    cl_prep_kernel<<<NROWS / 4, 256, 0, stream>>>(targets, tn);
    cl_rowloss_kernel<<<NROWS, 256, 0, stream>>>(preds, tn, neg_idx, row_loss);
    cl_reduce_kernel<<<1, 256, 0, stream>>>(row_loss, out);
}